// Round 2
// baseline (2002.026 us; speedup 1.0000x reference)
//
#include <hip/hip_runtime.h>
#include <hip/hip_bf16.h>

#define N_NODES 50000
#define NEDGE   800000
#define ETOT    850000   // edges + self loops

typedef unsigned int u32;
typedef unsigned short u16;

static __device__ __forceinline__ float b2f(u16 u) {
  union { u32 u; float f; } x; x.u = ((u32)u) << 16; return x.f;
}
static __device__ __forceinline__ u16 f2b(float f) {
  union { float f; u32 u; } x; x.f = f;
  u32 r = x.u + 0x7fffu + ((x.u >> 16) & 1u);
  return (u16)(r >> 16);
}
static __device__ __forceinline__ float lo_f(u32 p) {
  union { u32 u; float f; } x; x.u = p << 16; return x.f;
}
static __device__ __forceinline__ float hi_f(u32 p) {
  union { u32 u; float f; } x; x.u = p & 0xffff0000u; return x.f;
}
static __device__ __forceinline__ u32 pack_bf(float a, float b) {
  return (u32)f2b(a) | ((u32)f2b(b) << 16);
}
static __device__ __forceinline__ float sigm(float x) { return 1.f / (1.f + __expf(-x)); }
static __device__ __forceinline__ float tanh_f(float x) { return 1.f - 2.f / (__expf(2.f * x) + 1.f); }
static __device__ __forceinline__ float elu_f(float x) { return x > 0.f ? x : __expf(x) - 1.f; }

// ============ K1: fused temporal encoder ============
// GRU(24 steps) + per-step k/v projection (piggybacked on the h-matvec loop)
// + last-query MHA + out-proj + residual + proj -> writes xin = [x | t_emb].
// Wave = 2 nodes, lane = channel. h broadcast via per-wave LDS slot.
__global__ __launch_bounds__(256, 2) void k_temporal(
    const float* __restrict__ seq,
    const float* __restrict__ w_ih, const float* __restrict__ w_hh,
    const float* __restrict__ b_ih, const float* __restrict__ b_hh,
    const float* __restrict__ in_w, const float* __restrict__ in_b,
    const float* __restrict__ out_w, const float* __restrict__ out_b,
    const float* __restrict__ proj_w, const float* __restrict__ proj_b,
    const float* __restrict__ x, float* __restrict__ xin) {
  __shared__ float whh_t[64 * 194];   // [c2][g*64+j], pad 194: 4-way write conflict max
  __shared__ u32  wkv[64 * 64];       // packed bf16 {wk,wv} transposed: [d][lane]
  __shared__ float hbuf[4][2][64];
  int tid = threadIdx.x;
  // conflict-free LDS writes; uncoalesced global reads are L2-cached (48KB total)
  for (int i = tid; i < 12288; i += 256) {
    int c2 = i / 192, r = i - c2 * 192;
    whh_t[c2 * 194 + r] = w_hh[r * 64 + c2];
  }
  for (int i = tid; i < 4096; i += 256) {
    int d = i >> 6, j = i & 63;
    wkv[i] = pack_bf(in_w[(64 + j) * 64 + d], in_w[(128 + j) * 64 + d]);
  }
  int w = tid >> 6, lane = tid & 63;
  int gw = blockIdx.x * 4 + w;
  int n0 = gw * 2, n1 = gw * 2 + 1;

  float wih[3][16], bi[3], bh[3];
#pragma unroll
  for (int g = 0; g < 3; ++g) {
    bi[g] = b_ih[g * 64 + lane];
    bh[g] = b_hh[g * 64 + lane];
#pragma unroll
    for (int k = 0; k < 16; ++k) wih[g][k] = w_ih[(g * 64 + lane) * 16 + k];
  }
  float bk = in_b[64 + lane], bv = in_b[128 + lane];
  hbuf[w][0][lane] = 0.f; hbuf[w][1][lane] = 0.f;
  float hp0 = 0.f, hp1 = 0.f;
  __syncthreads();

  const float4* s0v = reinterpret_cast<const float4*>(seq + (size_t)n0 * 24 * 16);
  const float4* s1v = reinterpret_cast<const float4*>(seq + (size_t)n1 * 24 * 16);
  u32 kv0[24], kv1[24];

#pragma unroll
  for (int t = 0; t < 24; ++t) {
    float gi0[3], gi1[3], gh0[3], gh1[3];
#pragma unroll
    for (int g = 0; g < 3; ++g) { gi0[g] = bi[g]; gi1[g] = bi[g]; gh0[g] = bh[g]; gh1[g] = bh[g]; }
#pragma unroll
    for (int k4 = 0; k4 < 4; ++k4) {
      float4 a4 = s0v[t * 4 + k4], b4 = s1v[t * 4 + k4];
      float aa[4] = {a4.x, a4.y, a4.z, a4.w};
      float bb[4] = {b4.x, b4.y, b4.z, b4.w};
#pragma unroll
      for (int p = 0; p < 4; ++p) {
        int k = k4 * 4 + p;
#pragma unroll
        for (int g = 0; g < 3; ++g) { gi0[g] += aa[p] * wih[g][k]; gi1[g] += bb[p] * wih[g][k]; }
      }
    }
    if (t >= 1) {  // h_{t-1} matvec + piggybacked k/v projection of h_{t-1}
      float ka0 = 0.f, va0 = 0.f, ka1 = 0.f, va1 = 0.f;
      for (int c2 = 0; c2 < 64; ++c2) {
        float h0 = hbuf[w][0][c2], h1 = hbuf[w][1][c2];
        float wr = whh_t[c2 * 194 + lane];
        float wz = whh_t[c2 * 194 + 64 + lane];
        float wn = whh_t[c2 * 194 + 128 + lane];
        gh0[0] += h0 * wr; gh0[1] += h0 * wz; gh0[2] += h0 * wn;
        gh1[0] += h1 * wr; gh1[1] += h1 * wz; gh1[2] += h1 * wn;
        u32 pw = wkv[c2 * 64 + lane];
        float wk = lo_f(pw), wv = hi_f(pw);
        ka0 += h0 * wk; va0 += h0 * wv;
        ka1 += h1 * wk; va1 += h1 * wv;
      }
      kv0[t - 1] = pack_bf(ka0 + bk, va0 + bv);
      kv1[t - 1] = pack_bf(ka1 + bk, va1 + bv);
    }
    float r0 = sigm(gi0[0] + gh0[0]);
    float z0 = sigm(gi0[1] + gh0[1]);
    float nn0 = tanh_f(gi0[2] + r0 * gh0[2]);
    float h0n = (1.f - z0) * nn0 + z0 * hp0;
    float r1 = sigm(gi1[0] + gh1[0]);
    float z1 = sigm(gi1[1] + gh1[1]);
    float nn1 = tanh_f(gi1[2] + r1 * gh1[2]);
    float h1n = (1.f - z1) * nn1 + z1 * hp1;
    hbuf[w][0][lane] = h0n; hbuf[w][1][lane] = h1n;  // wave-synchronous
    hp0 = h0n; hp1 = h1n;
  }

  // reload wq^T / out_w^T / proj_w^T into the (dead) whh_t region
  __syncthreads();
  for (int i = tid; i < 4096; i += 256) {
    int d = i >> 6, j = i & 63;
    whh_t[i]        = in_w[j * 64 + d];
    whh_t[4096 + i] = out_w[j * 64 + d];
    whh_t[8192 + i] = proj_w[j * 64 + d];
  }
  __syncthreads();

  // k/v/q of h_23
  {
    float k0 = bk, v0 = bv, k1 = bk, v1 = bv;
    float q0 = in_b[lane], q1 = q0;
    for (int d = 0; d < 64; ++d) {
      float h0 = hbuf[w][0][d], h1 = hbuf[w][1][d];
      u32 pw = wkv[d * 64 + lane];
      float wk = lo_f(pw), wv = hi_f(pw);
      float wq = whh_t[d * 64 + lane];
      k0 += h0 * wk; v0 += h0 * wv; q0 += h0 * wq;
      k1 += h1 * wk; v1 += h1 * wv; q1 += h1 * wq;
    }
    kv0[23] = pack_bf(k0, v0);
    kv1[23] = pack_bf(k1, v1);

    // scores (head = lane>>4, reduce within 16-lane head group), softmax, PV
    float sc0[24], sc1[24];
#pragma unroll
    for (int t = 0; t < 24; ++t) {
      float s0 = q0 * lo_f(kv0[t]);
      float s1 = q1 * lo_f(kv1[t]);
      s0 += __shfl_xor(s0, 1, 16); s1 += __shfl_xor(s1, 1, 16);
      s0 += __shfl_xor(s0, 2, 16); s1 += __shfl_xor(s1, 2, 16);
      s0 += __shfl_xor(s0, 4, 16); s1 += __shfl_xor(s1, 4, 16);
      s0 += __shfl_xor(s0, 8, 16); s1 += __shfl_xor(s1, 8, 16);
      sc0[t] = s0 * 0.25f; sc1[t] = s1 * 0.25f;
    }
    float m0 = sc0[0], m1 = sc1[0];
#pragma unroll
    for (int t = 1; t < 24; ++t) { m0 = fmaxf(m0, sc0[t]); m1 = fmaxf(m1, sc1[t]); }
    float l0 = 0.f, o0 = 0.f, l1 = 0.f, o1 = 0.f;
#pragma unroll
    for (int t = 0; t < 24; ++t) {
      float p0 = __expf(sc0[t] - m0), p1 = __expf(sc1[t] - m1);
      l0 += p0; o0 += p0 * hi_f(kv0[t]);
      l1 += p1; o1 += p1 * hi_f(kv1[t]);
    }
    o0 /= l0; o1 /= l1;

    // out-proj + residual(h_23) + proj -> t_emb; assemble xin
    hbuf[w][0][lane] = o0; hbuf[w][1][lane] = o1;
    float a0 = out_b[lane], a1 = a0;
    for (int d = 0; d < 64; ++d) {
      float ow = whh_t[4096 + d * 64 + lane];
      a0 += hbuf[w][0][d] * ow;
      a1 += hbuf[w][1][d] * ow;
    }
    float last0 = hp0 + a0, last1 = hp1 + a1;
    hbuf[w][0][lane] = last0; hbuf[w][1][lane] = last1;
    float te0 = proj_b[lane], te1 = te0;
    for (int d = 0; d < 64; ++d) {
      float pw = whh_t[8192 + d * 64 + lane];
      te0 += hbuf[w][0][d] * pw;
      te1 += hbuf[w][1][d] * pw;
    }
    xin[(size_t)n0 * 128 + lane]      = x[(size_t)n0 * 64 + lane];
    xin[(size_t)n0 * 128 + 64 + lane] = te0;
    xin[(size_t)n1 * 128 + lane]      = x[(size_t)n1 * 64 + lane];
    xin[(size_t)n1 * 128 + 64 + lane] = te1;
  }
}

// ============ CSR construction ============
__global__ void k_zero(int* __restrict__ p, int n) {
  int i = blockIdx.x * 256 + threadIdx.x;
  if (i < n) p[i] = 0;
}
__global__ void k_count(const int* __restrict__ ei, int* __restrict__ rowptr) {
  int e = blockIdx.x * 256 + threadIdx.x;
  if (e >= ETOT) return;
  int d = (e < NEDGE) ? ei[NEDGE + e] : (e - NEDGE);
  atomicAdd(&rowptr[d + 1], 1);
}
__global__ void k_scan1(int* __restrict__ data, int* __restrict__ bsum, int n) {
  __shared__ int s[256];
  int i = blockIdx.x * 256 + threadIdx.x;
  s[threadIdx.x] = (i < n) ? data[i] : 0;
  __syncthreads();
  for (int off = 1; off < 256; off <<= 1) {
    int t = (threadIdx.x >= off) ? s[threadIdx.x - off] : 0;
    __syncthreads();
    s[threadIdx.x] += t;
    __syncthreads();
  }
  if (i < n) data[i] = s[threadIdx.x];
  if (threadIdx.x == 255) bsum[blockIdx.x] = s[255];
}
__global__ void k_scan2(int* __restrict__ bsum, int n) {
  __shared__ int s[256];
  int t = threadIdx.x;
  s[t] = (t < n) ? bsum[t] : 0;
  __syncthreads();
  for (int off = 1; off < 256; off <<= 1) {
    int v = (t >= off) ? s[t - off] : 0;
    __syncthreads();
    s[t] += v;
    __syncthreads();
  }
  if (t < n) bsum[t] = s[t];
}
__global__ void k_scan3(int* __restrict__ data, const int* __restrict__ bsum, int n) {
  int i = blockIdx.x * 256 + threadIdx.x;
  if (blockIdx.x > 0 && i < n) data[i] += bsum[blockIdx.x - 1];
}
__global__ void k_copycur(const int* __restrict__ rowptr, int* __restrict__ wcur, int n) {
  int i = blockIdx.x * 256 + threadIdx.x;
  if (i < n) wcur[i] = rowptr[i];
}
__global__ void k_scatter(const int* __restrict__ ei, int* __restrict__ wcur,
                          int* __restrict__ csr_src) {
  int e = blockIdx.x * 256 + threadIdx.x;
  if (e >= ETOT) return;
  int s = (e < NEDGE) ? ei[e] : (e - NEDGE);
  int d = (e < NEDGE) ? ei[NEDGE + e] : (e - NEDGE);
  int pos = atomicAdd(&wcur[d], 1);
  csr_src[pos] = s;
}

// ============ fp32 tiled GEMM: C[M,N] = A[M,K] @ B[K,N] ============
__global__ __launch_bounds__(256) void k_gemm(
    const float* __restrict__ A, const float* __restrict__ B,
    float* __restrict__ C, int M, int N, int K) {
  __shared__ float As[16][128 + 4];
  __shared__ float Bs[16][64];
  int tid = threadIdx.x;
  int tx = tid & 15, ty = tid >> 4;
  int row0 = blockIdx.y * 128, col0 = blockIdx.x * 64;
  float acc[8][4] = {};
  for (int k0 = 0; k0 < K; k0 += 16) {
#pragma unroll
    for (int i = tid; i < 128 * 16; i += 256) {
      int r = i >> 4, kk = i & 15;
      As[kk][r] = (row0 + r < M) ? A[(size_t)(row0 + r) * K + k0 + kk] : 0.f;
    }
#pragma unroll
    for (int i = tid; i < 16 * 64; i += 256) {
      int kk = i >> 6, c = i & 63;
      Bs[kk][c] = B[(size_t)(k0 + kk) * N + col0 + c];
    }
    __syncthreads();
#pragma unroll
    for (int kk = 0; kk < 16; ++kk) {
      float a[8], b[4];
#pragma unroll
      for (int i = 0; i < 8; ++i) a[i] = As[kk][ty * 8 + i];
#pragma unroll
      for (int j = 0; j < 4; ++j) b[j] = Bs[kk][tx * 4 + j];
#pragma unroll
      for (int i = 0; i < 8; ++i)
#pragma unroll
        for (int j = 0; j < 4; ++j) acc[i][j] += a[i] * b[j];
    }
    __syncthreads();
  }
#pragma unroll
  for (int i = 0; i < 8; ++i) {
    int r = row0 + ty * 8 + i;
    if (r < M) {
#pragma unroll
      for (int j = 0; j < 4; ++j) C[(size_t)r * N + col0 + tx * 4 + j] = acc[i][j];
    }
  }
}

// ============ per-node attention logits ============
__global__ __launch_bounds__(256) void k_att_scores(
    const float* __restrict__ ht, const float* __restrict__ att_s,
    const float* __restrict__ att_d, float* __restrict__ as_,
    float* __restrict__ ad_) {
  int w = threadIdx.x >> 6, lane = threadIdx.x & 63;
  int n = blockIdx.x * 4 + w;
#pragma unroll
  for (int h = 0; h < 4; ++h) {
    float v = ht[(size_t)n * 256 + h * 64 + lane];
    float ps = v * att_s[h * 64 + lane];
    float pd = v * att_d[h * 64 + lane];
#pragma unroll
    for (int off = 32; off >= 1; off >>= 1) {
      ps += __shfl_xor(ps, off);
      pd += __shfl_xor(pd, off);
    }
    if (lane == 0) { as_[n * 4 + h] = ps; ad_[n * 4 + h] = pd; }
  }
}

// ============ GAT aggregation (CSR in-edges, wave per node) ============
template <bool MEAN>
__global__ __launch_bounds__(256) void k_gat_agg(
    const float* __restrict__ ht, const float* __restrict__ as_,
    const float* __restrict__ ad_, const int* __restrict__ rowptr,
    const int* __restrict__ csr_src, const float* __restrict__ bias,
    float* __restrict__ out) {
  int w = threadIdx.x >> 6, lane = threadIdx.x & 63;
  int n = blockIdx.x * 4 + w;
  int hg = lane >> 4;
  float adh = ad_[n * 4 + hg];
  int beg = rowptr[n], end = rowptr[n + 1];
  float den = 0.f;
  float4 acc = make_float4(0.f, 0.f, 0.f, 0.f);
  for (int e = beg; e < end; ++e) {
    int s = csr_src[e];
    float ev = as_[s * 4 + hg] + adh;
    ev = ev > 0.f ? ev : 0.2f * ev;           // leaky_relu
    float p = __expf(ev);                     // no segment-max: logits bounded
    den += p;
    float4 hv = reinterpret_cast<const float4*>(ht)[(size_t)s * 64 + lane];
    acc.x += p * hv.x; acc.y += p * hv.y; acc.z += p * hv.z; acc.w += p * hv.w;
  }
  float inv = 1.f / den;
  if (!MEAN) {
    float4 b4 = reinterpret_cast<const float4*>(bias)[lane];
    float4 o;
    o.x = elu_f(acc.x * inv + b4.x);
    o.y = elu_f(acc.y * inv + b4.y);
    o.z = elu_f(acc.z * inv + b4.z);
    o.w = elu_f(acc.w * inv + b4.w);
    reinterpret_cast<float4*>(out)[(size_t)n * 64 + lane] = o;
  } else {
    float v0 = acc.x * inv, v1 = acc.y * inv, v2 = acc.z * inv, v3 = acc.w * inv;
    v0 += __shfl_xor(v0, 16); v0 += __shfl_xor(v0, 32);
    v1 += __shfl_xor(v1, 16); v1 += __shfl_xor(v1, 32);
    v2 += __shfl_xor(v2, 16); v2 += __shfl_xor(v2, 32);
    v3 += __shfl_xor(v3, 16); v3 += __shfl_xor(v3, 32);
    float4 b4 = reinterpret_cast<const float4*>(bias)[lane & 15];
    float4 o;
    o.x = elu_f(v0 * 0.25f + b4.x);
    o.y = elu_f(v1 * 0.25f + b4.y);
    o.z = elu_f(v2 * 0.25f + b4.z);
    o.w = elu_f(v3 * 0.25f + b4.w);
    if (lane < 16) reinterpret_cast<float4*>(out)[(size_t)n * 16 + lane] = o;
  }
}

// ============ final linear ============
__global__ __launch_bounds__(256) void k_final(
    const float* __restrict__ h2, const float* __restrict__ lin_w,
    const float* __restrict__ lin_b, float* __restrict__ out) {
  int w = threadIdx.x >> 6, lane = threadIdx.x & 63;
  int n = blockIdx.x * 4 + w;
  float p = h2[(size_t)n * 64 + lane] * lin_w[lane];
#pragma unroll
  for (int off = 32; off >= 1; off >>= 1) p += __shfl_xor(p, off);
  if (lane == 0) out[n] = p + lin_b[0];
}

extern "C" void kernel_launch(void* const* d_in, const int* in_sizes, int n_in,
                              void* d_out, int out_size, void* d_ws, size_t ws_size,
                              hipStream_t stream) {
  const float* x         = (const float*)d_in[0];
  const int*   ei        = (const int*)d_in[1];
  const float* seq       = (const float*)d_in[2];
  const float* gru_w_ih  = (const float*)d_in[3];
  const float* gru_w_hh  = (const float*)d_in[4];
  const float* gru_b_ih  = (const float*)d_in[5];
  const float* gru_b_hh  = (const float*)d_in[6];
  const float* attn_in_w = (const float*)d_in[7];
  const float* attn_in_b = (const float*)d_in[8];
  const float* attn_out_w= (const float*)d_in[9];
  const float* attn_out_b= (const float*)d_in[10];
  const float* proj_w    = (const float*)d_in[11];
  const float* proj_b    = (const float*)d_in[12];
  const float* gat1_w    = (const float*)d_in[13];
  const float* g1as      = (const float*)d_in[14];
  const float* g1ad      = (const float*)d_in[15];
  const float* gat1_b    = (const float*)d_in[16];
  const float* gat2_w    = (const float*)d_in[17];
  const float* g2as      = (const float*)d_in[18];
  const float* g2ad      = (const float*)d_in[19];
  const float* gat2_b    = (const float*)d_in[20];
  const float* lin_w     = (const float*)d_in[21];
  const float* lin_b     = (const float*)d_in[22];
  float* out = (float*)d_out;

  char* p = (char*)d_ws;
  auto alloc = [&](size_t bytes) {
    char* r = p;
    p += (bytes + 255) & ~(size_t)255;
    return r;
  };
  // peak live ~133 MB
  float* xin     = (float*)alloc((size_t)N_NODES * 128 * 4);  // reused as h2 later
  float* h1t     = (float*)alloc((size_t)N_NODES * 256 * 4);  // reused as h2t
  float* h1      = (float*)alloc((size_t)N_NODES * 256 * 4);
  float* as_     = (float*)alloc((size_t)N_NODES * 4 * 4);    // reused both layers
  float* ad_     = (float*)alloc((size_t)N_NODES * 4 * 4);
  int*   rowptr  = (int*)  alloc((size_t)(N_NODES + 1) * 4);
  int*   wcur    = (int*)  alloc((size_t)N_NODES * 4);
  int*   csr     = (int*)  alloc((size_t)ETOT * 4);
  int*   bsum    = (int*)  alloc(256 * 4);
  float* h2t = h1t;        // h1t dead after agg1
  float* h2  = xin;        // xin dead after gemm1

  // temporal encoder (fully fused)
  k_temporal<<<6250, 256, 0, stream>>>(seq, gru_w_ih, gru_w_hh, gru_b_ih, gru_b_hh,
                                       attn_in_w, attn_in_b, attn_out_w, attn_out_b,
                                       proj_w, proj_b, x, xin);
  // CSR (dst-sorted), shared by both GAT layers
  k_zero<<<196, 256, 0, stream>>>(rowptr, N_NODES + 1);
  k_count<<<(ETOT + 255) / 256, 256, 0, stream>>>(ei, rowptr);
  k_scan1<<<196, 256, 0, stream>>>(rowptr, bsum, N_NODES + 1);
  k_scan2<<<1, 256, 0, stream>>>(bsum, 196);
  k_scan3<<<196, 256, 0, stream>>>(rowptr, bsum, N_NODES + 1);
  k_copycur<<<(N_NODES + 255) / 256, 256, 0, stream>>>(rowptr, wcur, N_NODES);
  k_scatter<<<(ETOT + 255) / 256, 256, 0, stream>>>(ei, wcur, csr);
  // GAT1 (concat + elu)
  k_gemm<<<dim3(4, 391), 256, 0, stream>>>(xin, gat1_w, h1t, N_NODES, 256, 128);
  k_att_scores<<<12500, 256, 0, stream>>>(h1t, g1as, g1ad, as_, ad_);
  k_gat_agg<false><<<12500, 256, 0, stream>>>(h1t, as_, ad_, rowptr, csr, gat1_b, h1);
  // GAT2 (mean + elu)
  k_gemm<<<dim3(4, 391), 256, 0, stream>>>(h1, gat2_w, h2t, N_NODES, 256, 256);
  k_att_scores<<<12500, 256, 0, stream>>>(h2t, g2as, g2ad, as_, ad_);
  k_gat_agg<true><<<12500, 256, 0, stream>>>(h2t, as_, ad_, rowptr, csr, gat2_b, h2);
  // final
  k_final<<<12500, 256, 0, stream>>>(h2, lin_w, lin_b, out);
}

// Round 5
// 1002.580 us; speedup vs baseline: 1.9969x; 1.9969x over previous
//
#include <hip/hip_runtime.h>
#include <hip/hip_bf16.h>

#define N_NODES 50000
#define NEDGE   800000
#define ETOT    850000

typedef unsigned int u32;
typedef unsigned short u16;
typedef __attribute__((ext_vector_type(8))) short short8;
typedef __attribute__((ext_vector_type(4))) float f32x4;

union FragU { u32 u[4]; short8 s; };

static __device__ __forceinline__ u16 f2b(float f) {
  union { float f; u32 u; } x; x.f = f;
  u32 r = x.u + 0x7fffu + ((x.u >> 16) & 1u);
  return (u16)(r >> 16);
}
static __device__ __forceinline__ u32 pack_bf(float a, float b) {
  return (u32)f2b(a) | ((u32)f2b(b) << 16);
}
static __device__ __forceinline__ u32 cvtpk(float lo, float hi) {
  u32 r; asm("v_cvt_pk_bf16_f32 %0, %1, %2" : "=v"(r) : "v"(lo), "v"(hi));
  return r;
}
static __device__ __forceinline__ short8 mk4(u32 a, u32 b, u32 c, u32 d) {
  FragU f; f.u[0] = a; f.u[1] = b; f.u[2] = c; f.u[3] = d; return f.s;
}
static __device__ __forceinline__ short8 ldfrag(const u32* p) {
  uint4 v = *(const uint4*)p;
  FragU f; f.u[0] = v.x; f.u[1] = v.y; f.u[2] = v.z; f.u[3] = v.w; return f.s;
}
static __device__ __forceinline__ f32x4 mfma16(short8 a, short8 b, f32x4 c) {
  return __builtin_amdgcn_mfma_f32_16x16x32_bf16(a, b, c, 0, 0, 0);
}
static __device__ __forceinline__ float sigm(float x) { return 1.f / (1.f + __expf(-x)); }
static __device__ __forceinline__ float tanh_f(float x) { return 1.f - 2.f / (__expf(2.f * x) + 1.f); }
static __device__ __forceinline__ float elu_f(float x) { return x > 0.f ? x : __expf(x) - 1.f; }

// shared A/B k-slot bijection: slot(kt, g, j-pair) -> channel pair base
#define CH0(kt, g, j) (((kt) * 2 + ((j) >> 1)) * 16 + (g) * 4 + ((j) & 1) * 2)

// ============ K1: MFMA GRU ============
// Operand-swapped: D[ch][node] = sum_k W[ch][k] * h[k][node].
// Wave = 32 nodes (2 N-tiles). h stays in registers across all 24 steps:
// C-layout -> next-step B-frags is a pure per-lane cvt_pk repack (bijection).
// Biases folded into a constant-1.0 K-slot of the gi MFMA (b_hh_n added in
// elementwise since the n-gate needs r * (gh_n + b_hh_n)).
__global__ __launch_bounds__(128, 2) void k_gru(
    const float* __restrict__ seq, const float* __restrict__ w_ih,
    const float* __restrict__ w_hh, const float* __restrict__ b_ih,
    const float* __restrict__ b_hh, u32* __restrict__ gru_h,
    float* __restrict__ h_last) {
  __shared__ u32 frg[36 * 256];  // 36KB: frags 0..11 = gi, 12+(mt*2+kt) = gh
  int tid = threadIdx.x;
  for (int i = tid; i < 36 * 256; i += 128) {
    int v = i & 3, lane = (i >> 2) & 63, f = i >> 8;
    int g = lane >> 4, mm = lane & 15;
    u32 val = 0u;
    if (f < 12) {
      int gate = f * 16 + mm;
      if (g < 2) {
        int dim = g * 8 + 2 * v;
        val = pack_bf(w_ih[gate * 16 + dim], w_ih[gate * 16 + dim + 1]);
      } else if (g == 2 && v == 0) {
        float bias = b_ih[gate] + (gate < 128 ? b_hh[gate] : 0.f);
        val = pack_bf(bias, 0.f);
      }
    } else {
      int ff = f - 12, mt = ff >> 1, kt = ff & 1;
      int gate = mt * 16 + mm;
      int ch0 = CH0(kt, g, v);
      val = pack_bf(w_hh[gate * 64 + ch0], w_hh[gate * 64 + ch0 + 1]);
    }
    frg[i] = val;
  }
  __syncthreads();
  int w = tid >> 6, lane = tid & 63, g = lane >> 4, m = lane & 15;
  int n0 = (blockIdx.x * 2 + w) * 32;
  const f32x4 Z = {0.f, 0.f, 0.f, 0.f};

  float bhn[4][4];
#pragma unroll
  for (int mt = 0; mt < 4; ++mt)
#pragma unroll
    for (int r = 0; r < 4; ++r) bhn[mt][r] = b_hh[128 + mt * 16 + g * 4 + r];

  f32x4 Hc[4][2];
  u32 hb[2][2][4];
#pragma unroll
  for (int a = 0; a < 4; ++a)
#pragma unroll
    for (int b = 0; b < 2; ++b) Hc[a][b] = Z;
#pragma unroll
  for (int a = 0; a < 2; ++a)
#pragma unroll
    for (int b = 0; b < 2; ++b)
#pragma unroll
      for (int c = 0; c < 4; ++c) hb[a][b][c] = 0u;

  int node[2];
#pragma unroll
  for (int nt = 0; nt < 2; ++nt) {
    int n = n0 + nt * 16 + m;
    node[nt] = n < N_NODES ? n : (N_NODES - 1);
  }

  for (int t = 0; t < 24; ++t) {
    // seq B-frags (K=16 in slots 0..15; slot16 = 1.0 bias lane)
    u32 sf[2][4];
#pragma unroll
    for (int nt = 0; nt < 2; ++nt) {
      if (g < 2) {
        const float4* sp = (const float4*)seq + (size_t)node[nt] * 96 + t * 4 + g * 2;
        float4 a4 = sp[0], b4 = sp[1];
        sf[nt][0] = cvtpk(a4.x, a4.y); sf[nt][1] = cvtpk(a4.z, a4.w);
        sf[nt][2] = cvtpk(b4.x, b4.y); sf[nt][3] = cvtpk(b4.z, b4.w);
      } else if (g == 2) {
        sf[nt][0] = 0x00003f80u; sf[nt][1] = 0u; sf[nt][2] = 0u; sf[nt][3] = 0u;
      } else {
        sf[nt][0] = 0u; sf[nt][1] = 0u; sf[nt][2] = 0u; sf[nt][3] = 0u;
      }
    }
    f32x4 Crz[8][2], Cgn[4][2], Cghn[4][2];
    // gi phase (+ folded biases)
#pragma unroll
    for (int mt = 0; mt < 12; ++mt) {
      short8 a = ldfrag(&frg[(mt * 64 + lane) * 4]);
#pragma unroll
      for (int nt = 0; nt < 2; ++nt) {
        f32x4 c = mfma16(a, mk4(sf[nt][0], sf[nt][1], sf[nt][2], sf[nt][3]), Z);
        if (mt < 8) Crz[mt][nt] = c; else Cgn[mt - 8][nt] = c;
      }
    }
    // gh kt=0
#pragma unroll
    for (int mt = 0; mt < 12; ++mt) {
      short8 a = ldfrag(&frg[((12 + mt * 2) * 64 + lane) * 4]);
#pragma unroll
      for (int nt = 0; nt < 2; ++nt) {
        short8 b = mk4(hb[0][nt][0], hb[0][nt][1], hb[0][nt][2], hb[0][nt][3]);
        if (mt < 8) Crz[mt][nt] = mfma16(a, b, Crz[mt][nt]);
        else Cghn[mt - 8][nt] = mfma16(a, b, Z);
      }
    }
    // gh kt=1
#pragma unroll
    for (int mt = 0; mt < 12; ++mt) {
      short8 a = ldfrag(&frg[((12 + mt * 2 + 1) * 64 + lane) * 4]);
#pragma unroll
      for (int nt = 0; nt < 2; ++nt) {
        short8 b = mk4(hb[1][nt][0], hb[1][nt][1], hb[1][nt][2], hb[1][nt][3]);
        if (mt < 8) Crz[mt][nt] = mfma16(a, b, Crz[mt][nt]);
        else Cghn[mt - 8][nt] = mfma16(a, b, Cghn[mt - 8][nt]);
      }
    }
    // elementwise + repack + store
#pragma unroll
    for (int nt = 0; nt < 2; ++nt) {
      int n = n0 + nt * 16 + m;
      bool ok = n < N_NODES;
#pragma unroll
      for (int mt = 0; mt < 4; ++mt) {
#pragma unroll
        for (int r = 0; r < 4; ++r) {
          float rr = sigm(Crz[mt][nt][r]);
          float zz = sigm(Crz[mt + 4][nt][r]);
          float gn = Cgn[mt][nt][r] + rr * (Cghn[mt][nt][r] + bhn[mt][r]);
          float nn = tanh_f(gn);
          Hc[mt][nt][r] = nn + zz * (Hc[mt][nt][r] - nn);
        }
      }
#pragma unroll
      for (int kt = 0; kt < 2; ++kt) {
        hb[kt][nt][0] = cvtpk(Hc[2 * kt][nt][0], Hc[2 * kt][nt][1]);
        hb[kt][nt][1] = cvtpk(Hc[2 * kt][nt][2], Hc[2 * kt][nt][3]);
        hb[kt][nt][2] = cvtpk(Hc[2 * kt + 1][nt][0], Hc[2 * kt + 1][nt][1]);
        hb[kt][nt][3] = cvtpk(Hc[2 * kt + 1][nt][2], Hc[2 * kt + 1][nt][3]);
      }
      if (ok) {
        u32* outp = gru_h + ((size_t)n * 24 + t) * 32;
#pragma unroll
        for (int kt = 0; kt < 2; ++kt)
#pragma unroll
          for (int j = 0; j < 4; ++j) outp[CH0(kt, g, j) >> 1] = hb[kt][nt][j];
      }
    }
  }
#pragma unroll
  for (int nt = 0; nt < 2; ++nt) {
    int n = n0 + nt * 16 + m;
    if (n < N_NODES) {
#pragma unroll
      for (int mt = 0; mt < 4; ++mt)
#pragma unroll
        for (int r = 0; r < 4; ++r)
          h_last[(size_t)n * 64 + mt * 16 + g * 4 + r] = Hc[mt][nt][r];
    }
  }
}

// ============ K2: fold Wq/Wk/bq + scale into M (64x256) and abk (256) ============
// s[t] = h23^T M_h h_t + abk_h . h_t  (+ const-in-t terms, dropped: softmax-invariant)
__global__ void k_prep(const float* __restrict__ aw, const float* __restrict__ ab,
                       float* __restrict__ Mall, float* __restrict__ abk) {
  int j = threadIdx.x;
  int h = j >> 6, cp = j & 63;
  if (blockIdx.x < 64) {
    int c = blockIdx.x;
    float acc = 0.f;
    for (int d = 0; d < 16; ++d)
      acc += aw[(h * 16 + d) * 64 + c] * aw[(64 + h * 16 + d) * 64 + cp];
    Mall[c * 256 + j] = 0.25f * acc;
  } else {
    float acc = 0.f;
    for (int d = 0; d < 16; ++d)
      acc += ab[h * 16 + d] * aw[(64 + h * 16 + d) * 64 + cp];
    abk[j] = 0.25f * acc;
  }
}

// ============ K3: U[n][256] = h23 @ Mall + abk (bf16 out) ============
__global__ __launch_bounds__(256, 2) void k_ugemm(
    const float* __restrict__ Mall, const float* __restrict__ abk,
    const float* __restrict__ h_last, u32* __restrict__ U) {
  __shared__ u32 frg[32 * 256];  // 32KB
  __shared__ float abks[256];
  int tid = threadIdx.x;
  for (int i = tid; i < 32 * 256; i += 256) {
    int v = i & 3, lane = (i >> 2) & 63, f = i >> 8;
    int kt = f & 1, mt = f >> 1;
    int g = lane >> 4, mm = lane & 15;
    int jj = mt * 16 + mm;
    int ch0 = CH0(kt, g, v);
    frg[i] = pack_bf(Mall[ch0 * 256 + jj], Mall[(ch0 + 1) * 256 + jj]);
  }
  if (tid < 256) abks[tid] = abk[tid];
  __syncthreads();
  int w = tid >> 6, lane = tid & 63, g = lane >> 4, m = lane & 15;
  int n0 = blockIdx.x * 128 + w * 32;
  u32 hbf[2][2][4];
#pragma unroll
  for (int nt = 0; nt < 2; ++nt) {
    int n = n0 + nt * 16 + m;
    int nc = n < N_NODES ? n : N_NODES - 1;
#pragma unroll
    for (int kt = 0; kt < 2; ++kt)
#pragma unroll
      for (int j = 0; j < 4; ++j) {
        int ch0 = CH0(kt, g, j);
        float2 hv = *(const float2*)&h_last[(size_t)nc * 64 + ch0];
        hbf[kt][nt][j] = cvtpk(hv.x, hv.y);
      }
  }
#pragma unroll
  for (int mt = 0; mt < 16; ++mt) {
    f32x4 C[2] = {{0.f, 0.f, 0.f, 0.f}, {0.f, 0.f, 0.f, 0.f}};
#pragma unroll
    for (int kt = 0; kt < 2; ++kt) {
      short8 a = ldfrag(&frg[((mt * 2 + kt) * 64 + lane) * 4]);
#pragma unroll
      for (int nt = 0; nt < 2; ++nt)
        C[nt] = mfma16(a, mk4(hbf[kt][nt][0], hbf[kt][nt][1], hbf[kt][nt][2], hbf[kt][nt][3]), C[nt]);
    }
    int j0 = mt * 16 + g * 4;
    f32x4 av = *(const f32x4*)&abks[j0];
#pragma unroll
    for (int nt = 0; nt < 2; ++nt) {
      int n = n0 + nt * 16 + m;
      if (n < N_NODES) {
        U[(size_t)n * 128 + (j0 >> 1)] = cvtpk(C[nt][0] + av[0], C[nt][1] + av[1]);
        U[(size_t)n * 128 + (j0 >> 1) + 1] = cvtpk(C[nt][2] + av[2], C[nt][3] + av[3]);
      }
    }
  }
}

// ============ K4: per-node attention (scores + V via MFMA) + projections -> xin ============
__global__ __launch_bounds__(256, 2) void k_attn2(
    const u32* __restrict__ gru_h, const u32* __restrict__ U,
    const float* __restrict__ aw, const float* __restrict__ ab,
    const float* __restrict__ out_w, const float* __restrict__ out_b,
    const float* __restrict__ proj_w, const float* __restrict__ proj_b,
    const float* __restrict__ h_last, const float* __restrict__ x,
    float* __restrict__ xin) {
  __shared__ u32 vfrg[8 * 256];  // 8KB Wv frags
  __shared__ float olds[4][64];
  __shared__ float llds[4][64];
  int tid = threadIdx.x;
  for (int i = tid; i < 8 * 256; i += 256) {
    int v = i & 3, lane = (i >> 2) & 63, f = i >> 8;
    int kt = f & 1, mt = f >> 1;
    int g = lane >> 4, mm = lane & 15;
    int vo = mt * 16 + mm;
    int ch0 = CH0(kt, g, v);
    vfrg[i] = pack_bf(aw[(128 + vo) * 64 + ch0], aw[(128 + vo) * 64 + ch0 + 1]);
  }
  __syncthreads();
  int w = tid >> 6, lane = tid & 63, g = lane >> 4, m = lane & 15;
  f32x4 owr[16], pwr[16];
#pragma unroll
  for (int d = 0; d < 16; ++d) {
    owr[d] = *(const f32x4*)&out_w[lane * 64 + d * 4];
    pwr[d] = *(const f32x4*)&proj_w[lane * 64 + d * 4];
  }
  float ob = out_b[lane], pbias = proj_b[lane];
  float obv = 0.f;
#pragma unroll
  for (int d = 0; d < 16; ++d) {
    f32x4 bv4 = *(const f32x4*)&ab[128 + d * 4];
    obv += bv4[0] * owr[d][0] + bv4[1] * owr[d][1] + bv4[2] * owr[d][2] + bv4[3] * owr[d][3];
  }
  int stride = gridDim.x * 4;
  for (int n = blockIdx.x * 4 + w; n < N_NODES; n += stride) {
    u32 uf[2][4] = {{0u, 0u, 0u, 0u}, {0u, 0u, 0u, 0u}};
    if (m < 4) {
#pragma unroll
      for (int kt = 0; kt < 2; ++kt)
#pragma unroll
        for (int j = 0; j < 4; ++j)
          uf[kt][j] = U[(size_t)n * 128 + m * 32 + (CH0(kt, g, j) >> 1)];
    }
    u32 hf[2][2][4];
#pragma unroll
    for (int tt = 0; tt < 2; ++tt) {
      int t = tt * 16 + m;
      bool okt = t < 24;
#pragma unroll
      for (int kt = 0; kt < 2; ++kt)
#pragma unroll
        for (int j = 0; j < 4; ++j)
          hf[tt][kt][j] = okt ? gru_h[((size_t)n * 24 + t) * 32 + (CH0(kt, g, j) >> 1)] : 0u;
    }
    f32x4 S0 = {0.f, 0.f, 0.f, 0.f}, S1 = {0.f, 0.f, 0.f, 0.f};
#pragma unroll
    for (int kt = 0; kt < 2; ++kt) {
      short8 a = mk4(uf[kt][0], uf[kt][1], uf[kt][2], uf[kt][3]);
      S0 = mfma16(a, mk4(hf[0][kt][0], hf[0][kt][1], hf[0][kt][2], hf[0][kt][3]), S0);
      S1 = mfma16(a, mk4(hf[1][kt][0], hf[1][kt][1], hf[1][kt][2], hf[1][kt][3]), S1);
    }
    float p0[4], p1[4], pb0[4], pb1[4], den[4];
#pragma unroll
    for (int r = 0; r < 4; ++r) {
      p0[r] = __expf(S0[r]);
      p1[r] = (m < 8) ? __expf(S1[r]) : 0.f;
    }
#pragma unroll
    for (int r = 0; r < 4; ++r) {
      pb0[r] = __shfl(p0[r], m);
      pb1[r] = __shfl(p1[r], m);
      float s = pb0[r] + pb1[r];
      s += __shfl_xor(s, 1); s += __shfl_xor(s, 2);
      s += __shfl_xor(s, 4); s += __shfl_xor(s, 8);
      den[r] = s;
    }
    f32x4 part[4];
#pragma unroll
    for (int mt = 0; mt < 4; ++mt) part[mt] = f32x4{0.f, 0.f, 0.f, 0.f};
#pragma unroll
    for (int tt = 0; tt < 2; ++tt) {
#pragma unroll
      for (int mt = 0; mt < 4; ++mt) {
        f32x4 Vc = {0.f, 0.f, 0.f, 0.f};
#pragma unroll
        for (int kt = 0; kt < 2; ++kt) {
          short8 a = ldfrag(&vfrg[((mt * 2 + kt) * 64 + lane) * 4]);
          Vc = mfma16(a, mk4(hf[tt][kt][0], hf[tt][kt][1], hf[tt][kt][2], hf[tt][kt][3]), Vc);
        }
        float pw_ = tt == 0 ? pb0[mt] : pb1[mt];
#pragma unroll
        for (int r = 0; r < 4; ++r) part[mt][r] += Vc[r] * pw_;
      }
    }
#pragma unroll
    for (int mt = 0; mt < 4; ++mt)
#pragma unroll
      for (int r = 0; r < 4; ++r) {
        float v = part[mt][r];
        v += __shfl_xor(v, 1); v += __shfl_xor(v, 2);
        v += __shfl_xor(v, 4); v += __shfl_xor(v, 8);
        part[mt][r] = v;
      }
    if (m == 0) {
#pragma unroll
      for (int mt = 0; mt < 4; ++mt) {
        float inv = 1.f / den[mt];
#pragma unroll
        for (int r = 0; r < 4; ++r)
          olds[w][mt * 16 + g * 4 + r] = part[mt][r] * inv;
      }
    }
    float ao = ob + obv;
#pragma unroll
    for (int d = 0; d < 16; ++d) {
      f32x4 o4 = *(const f32x4*)&olds[w][d * 4];
      ao += o4[0] * owr[d][0] + o4[1] * owr[d][1] + o4[2] * owr[d][2] + o4[3] * owr[d][3];
    }
    float last = h_last[(size_t)n * 64 + lane] + ao;
    llds[w][lane] = last;
    float te = pbias;
#pragma unroll
    for (int d = 0; d < 16; ++d) {
      f32x4 l4 = *(const f32x4*)&llds[w][d * 4];
      te += l4[0] * pwr[d][0] + l4[1] * pwr[d][1] + l4[2] * pwr[d][2] + l4[3] * pwr[d][3];
    }
    xin[(size_t)n * 128 + lane] = x[(size_t)n * 64 + lane];
    xin[(size_t)n * 128 + 64 + lane] = te;
  }
}

// ============ CSR construction (unchanged) ============
__global__ void k_zero(int* __restrict__ p, int n) {
  int i = blockIdx.x * 256 + threadIdx.x;
  if (i < n) p[i] = 0;
}
__global__ void k_count(const int* __restrict__ ei, int* __restrict__ rowptr) {
  int e = blockIdx.x * 256 + threadIdx.x;
  if (e >= ETOT) return;
  int d = (e < NEDGE) ? ei[NEDGE + e] : (e - NEDGE);
  atomicAdd(&rowptr[d + 1], 1);
}
__global__ void k_scan1(int* __restrict__ data, int* __restrict__ bsum, int n) {
  __shared__ int s[256];
  int i = blockIdx.x * 256 + threadIdx.x;
  s[threadIdx.x] = (i < n) ? data[i] : 0;
  __syncthreads();
  for (int off = 1; off < 256; off <<= 1) {
    int t = (threadIdx.x >= off) ? s[threadIdx.x - off] : 0;
    __syncthreads();
    s[threadIdx.x] += t;
    __syncthreads();
  }
  if (i < n) data[i] = s[threadIdx.x];
  if (threadIdx.x == 255) bsum[blockIdx.x] = s[255];
}
__global__ void k_scan2(int* __restrict__ bsum, int n) {
  __shared__ int s[256];
  int t = threadIdx.x;
  s[t] = (t < n) ? bsum[t] : 0;
  __syncthreads();
  for (int off = 1; off < 256; off <<= 1) {
    int v = (t >= off) ? s[t - off] : 0;
    __syncthreads();
    s[t] += v;
    __syncthreads();
  }
  if (t < n) bsum[t] = s[t];
}
__global__ void k_scan3(int* __restrict__ data, const int* __restrict__ bsum, int n) {
  int i = blockIdx.x * 256 + threadIdx.x;
  if (blockIdx.x > 0 && i < n) data[i] += bsum[blockIdx.x - 1];
}
__global__ void k_copycur(const int* __restrict__ rowptr, int* __restrict__ wcur, int n) {
  int i = blockIdx.x * 256 + threadIdx.x;
  if (i < n) wcur[i] = rowptr[i];
}
__global__ void k_scatter(const int* __restrict__ ei, int* __restrict__ wcur,
                          int* __restrict__ csr_src) {
  int e = blockIdx.x * 256 + threadIdx.x;
  if (e >= ETOT) return;
  int s = (e < NEDGE) ? ei[e] : (e - NEDGE);
  int d = (e < NEDGE) ? ei[NEDGE + e] : (e - NEDGE);
  int pos = atomicAdd(&wcur[d], 1);
  csr_src[pos] = s;
}

// ============ GAT node transform: Cout[n][256] = A[n][KT*32] @ W, MFMA bf16 ============
template <int KT>
__global__ __launch_bounds__(256, 2) void k_gat_gemm(
    const float* __restrict__ A, const float* __restrict__ W,
    float* __restrict__ Cout) {
  __shared__ u32 frg[8 * KT * 256];  // KT=4: 32KB, KT=8: 64KB
  int tid = threadIdx.x;
  int mt0 = blockIdx.y * 8;
  const int CIN = KT * 32;   // KT counts K=32 MFMA chunks
  for (int i = tid; i < 8 * KT * 256; i += 256) {
    int v = i & 3, lane = (i >> 2) & 63, f = i >> 8;
    int kt = f % KT, mt = f / KT;
    int g = lane >> 4, mm = lane & 15;
    int o = (mt0 + mt) * 16 + mm;
    int ch0 = CH0(kt, g, v);
    frg[i] = pack_bf(W[ch0 * 256 + o], W[(ch0 + 1) * 256 + o]);
  }
  __syncthreads();
  int w = tid >> 6, lane = tid & 63, g = lane >> 4, m = lane & 15;
  int n0 = blockIdx.x * 128 + w * 32;
  u32 bfr[2][KT][4];
#pragma unroll
  for (int nt = 0; nt < 2; ++nt) {
    int n = n0 + nt * 16 + m;
    int nc = n < N_NODES ? n : N_NODES - 1;
#pragma unroll
    for (int kt = 0; kt < KT; ++kt)
#pragma unroll
      for (int j = 0; j < 4; ++j) {
        int ch0 = CH0(kt, g, j);
        float2 xv = *(const float2*)&A[(size_t)nc * CIN + ch0];
        bfr[nt][kt][j] = cvtpk(xv.x, xv.y);
      }
  }
#pragma unroll
  for (int mt = 0; mt < 8; ++mt) {
    f32x4 C[2] = {{0.f, 0.f, 0.f, 0.f}, {0.f, 0.f, 0.f, 0.f}};
#pragma unroll
    for (int kt = 0; kt < KT; ++kt) {
      short8 a = ldfrag(&frg[((mt * KT + kt) * 64 + lane) * 4]);
#pragma unroll
      for (int nt = 0; nt < 2; ++nt)
        C[nt] = mfma16(a, mk4(bfr[nt][kt][0], bfr[nt][kt][1], bfr[nt][kt][2], bfr[nt][kt][3]), C[nt]);
    }
#pragma unroll
    for (int nt = 0; nt < 2; ++nt) {
      int n = n0 + nt * 16 + m;
      if (n < N_NODES) {
        int o0 = (mt0 + mt) * 16 + g * 4;
        *(f32x4*)&Cout[(size_t)n * 256 + o0] = C[nt];
      }
    }
  }
}

// ============ per-node attention logits (unchanged) ============
__global__ __launch_bounds__(256) void k_att_scores(
    const float* __restrict__ ht, const float* __restrict__ att_s,
    const float* __restrict__ att_d, float* __restrict__ as_,
    float* __restrict__ ad_) {
  int w = threadIdx.x >> 6, lane = threadIdx.x & 63;
  int n = blockIdx.x * 4 + w;
#pragma unroll
  for (int h = 0; h < 4; ++h) {
    float v = ht[(size_t)n * 256 + h * 64 + lane];
    float ps = v * att_s[h * 64 + lane];
    float pd = v * att_d[h * 64 + lane];
#pragma unroll
    for (int off = 32; off >= 1; off >>= 1) {
      ps += __shfl_xor(ps, off);
      pd += __shfl_xor(pd, off);
    }
    if (lane == 0) { as_[n * 4 + h] = ps; ad_[n * 4 + h] = pd; }
  }
}

// ============ GAT aggregation (unchanged) ============
template <bool MEAN>
__global__ __launch_bounds__(256) void k_gat_agg(
    const float* __restrict__ ht, const float* __restrict__ as_,
    const float* __restrict__ ad_, const int* __restrict__ rowptr,
    const int* __restrict__ csr_src, const float* __restrict__ bias,
    float* __restrict__ out) {
  int w = threadIdx.x >> 6, lane = threadIdx.x & 63;
  int n = blockIdx.x * 4 + w;
  int hg = lane >> 4;
  float adh = ad_[n * 4 + hg];
  int beg = rowptr[n], end = rowptr[n + 1];
  float den = 0.f;
  float4 acc = make_float4(0.f, 0.f, 0.f, 0.f);
  for (int e = beg; e < end; ++e) {
    int s = csr_src[e];
    float ev = as_[s * 4 + hg] + adh;
    ev = ev > 0.f ? ev : 0.2f * ev;
    float p = __expf(ev);
    den += p;
    float4 hv = reinterpret_cast<const float4*>(ht)[(size_t)s * 64 + lane];
    acc.x += p * hv.x; acc.y += p * hv.y; acc.z += p * hv.z; acc.w += p * hv.w;
  }
  float inv = 1.f / den;
  if (!MEAN) {
    float4 b4 = reinterpret_cast<const float4*>(bias)[lane];
    float4 o;
    o.x = elu_f(acc.x * inv + b4.x);
    o.y = elu_f(acc.y * inv + b4.y);
    o.z = elu_f(acc.z * inv + b4.z);
    o.w = elu_f(acc.w * inv + b4.w);
    reinterpret_cast<float4*>(out)[(size_t)n * 64 + lane] = o;
  } else {
    float v0 = acc.x * inv, v1 = acc.y * inv, v2 = acc.z * inv, v3 = acc.w * inv;
    v0 += __shfl_xor(v0, 16); v0 += __shfl_xor(v0, 32);
    v1 += __shfl_xor(v1, 16); v1 += __shfl_xor(v1, 32);
    v2 += __shfl_xor(v2, 16); v2 += __shfl_xor(v2, 32);
    v3 += __shfl_xor(v3, 16); v3 += __shfl_xor(v3, 32);
    float4 b4 = reinterpret_cast<const float4*>(bias)[lane & 15];
    float4 o;
    o.x = elu_f(v0 * 0.25f + b4.x);
    o.y = elu_f(v1 * 0.25f + b4.y);
    o.z = elu_f(v2 * 0.25f + b4.z);
    o.w = elu_f(v3 * 0.25f + b4.w);
    if (lane < 16) reinterpret_cast<float4*>(out)[(size_t)n * 16 + lane] = o;
  }
}

// ============ final linear (unchanged) ============
__global__ __launch_bounds__(256) void k_final(
    const float* __restrict__ h2, const float* __restrict__ lin_w,
    const float* __restrict__ lin_b, float* __restrict__ out) {
  int w = threadIdx.x >> 6, lane = threadIdx.x & 63;
  int n = blockIdx.x * 4 + w;
  float p = h2[(size_t)n * 64 + lane] * lin_w[lane];
#pragma unroll
  for (int off = 32; off >= 1; off >>= 1) p += __shfl_xor(p, off);
  if (lane == 0) out[n] = p + lin_b[0];
}

extern "C" void kernel_launch(void* const* d_in, const int* in_sizes, int n_in,
                              void* d_out, int out_size, void* d_ws, size_t ws_size,
                              hipStream_t stream) {
  const float* x         = (const float*)d_in[0];
  const int*   ei        = (const int*)d_in[1];
  const float* seq       = (const float*)d_in[2];
  const float* gru_w_ih  = (const float*)d_in[3];
  const float* gru_w_hh  = (const float*)d_in[4];
  const float* gru_b_ih  = (const float*)d_in[5];
  const float* gru_b_hh  = (const float*)d_in[6];
  const float* attn_in_w = (const float*)d_in[7];
  const float* attn_in_b = (const float*)d_in[8];
  const float* attn_out_w= (const float*)d_in[9];
  const float* attn_out_b= (const float*)d_in[10];
  const float* proj_w    = (const float*)d_in[11];
  const float* proj_b    = (const float*)d_in[12];
  const float* gat1_w    = (const float*)d_in[13];
  const float* g1as      = (const float*)d_in[14];
  const float* g1ad      = (const float*)d_in[15];
  const float* gat1_b    = (const float*)d_in[16];
  const float* gat2_w    = (const float*)d_in[17];
  const float* g2as      = (const float*)d_in[18];
  const float* g2ad      = (const float*)d_in[19];
  const float* gat2_b    = (const float*)d_in[20];
  const float* lin_w     = (const float*)d_in[21];
  const float* lin_b     = (const float*)d_in[22];
  float* out = (float*)d_out;

  char* p = (char*)d_ws;
  auto alloc = [&](size_t bytes) {
    char* r = p;
    p += (bytes + 255) & ~(size_t)255;
    return r;
  };
  // region0 hosts gru_h (phase 1), then h1t + h1 (phase 2). Peak ws ~222MB.
  char*  region0 = alloc((size_t)N_NODES * 24 * 64 * 2);       // 153.6 MB
  float* h_last  = (float*)alloc((size_t)N_NODES * 64 * 4);    // 12.8 MB
  u32*   U       = (u32*)  alloc((size_t)N_NODES * 256 * 2);   // 25.6 MB
  float* xin     = (float*)alloc((size_t)N_NODES * 128 * 4);   // 25.6 MB
  float* Mall    = (float*)alloc(64 * 256 * 4);
  float* abk     = (float*)alloc(256 * 4);
  float* as_     = (float*)alloc((size_t)N_NODES * 4 * 4);
  float* ad_     = (float*)alloc((size_t)N_NODES * 4 * 4);
  int*   rowptr  = (int*)  alloc((size_t)(N_NODES + 1) * 4);
  int*   wcur    = (int*)  alloc((size_t)N_NODES * 4);
  int*   csr     = (int*)  alloc((size_t)ETOT * 4);
  int*   bsum    = (int*)  alloc(256 * 4);
  u32*   gru_h = (u32*)region0;
  float* h1t   = (float*)region0;                       // 51.2 MB (gru_h dead)
  float* h1    = (float*)(region0 + ((size_t)64 << 20)); // 51.2 MB at +64MB
  float* h2    = xin;                                   // 12.8 MB (xin dead)

  // temporal encoder (MFMA)
  k_gru<<<782, 128, 0, stream>>>(seq, gru_w_ih, gru_w_hh, gru_b_ih, gru_b_hh,
                                 gru_h, h_last);
  k_prep<<<65, 256, 0, stream>>>(attn_in_w, attn_in_b, Mall, abk);
  k_ugemm<<<391, 256, 0, stream>>>(Mall, abk, h_last, U);
  k_attn2<<<391, 256, 0, stream>>>(gru_h, U, attn_in_w, attn_in_b,
                                   attn_out_w, attn_out_b, proj_w, proj_b,
                                   h_last, x, xin);
  // CSR (dst-sorted), shared by both GAT layers
  k_zero<<<196, 256, 0, stream>>>(rowptr, N_NODES + 1);
  k_count<<<(ETOT + 255) / 256, 256, 0, stream>>>(ei, rowptr);
  k_scan1<<<196, 256, 0, stream>>>(rowptr, bsum, N_NODES + 1);
  k_scan2<<<1, 256, 0, stream>>>(bsum, 196);
  k_scan3<<<196, 256, 0, stream>>>(rowptr, bsum, N_NODES + 1);
  k_copycur<<<(N_NODES + 255) / 256, 256, 0, stream>>>(rowptr, wcur, N_NODES);
  k_scatter<<<(ETOT + 255) / 256, 256, 0, stream>>>(ei, wcur, csr);
  // GAT1 (concat + elu)
  k_gat_gemm<4><<<dim3(391, 2), 256, 0, stream>>>(xin, gat1_w, h1t);
  k_att_scores<<<12500, 256, 0, stream>>>(h1t, g1as, g1ad, as_, ad_);
  k_gat_agg<false><<<12500, 256, 0, stream>>>(h1t, as_, ad_, rowptr, csr, gat1_b, h1);
  // GAT2 (mean + elu) — h2t reuses h1t region
  k_gat_gemm<8><<<dim3(391, 2), 256, 0, stream>>>(h1, gat2_w, h1t);
  k_att_scores<<<12500, 256, 0, stream>>>(h1t, g2as, g2ad, as_, ad_);
  k_gat_agg<true><<<12500, 256, 0, stream>>>(h1t, as_, ad_, rowptr, csr, gat2_b, h2);
  // final
  k_final<<<12500, 256, 0, stream>>>(h2, lin_w, lin_b, out);
}